// Round 1
// baseline (504.667 us; speedup 1.0000x reference)
//
#include <hip/hip_runtime.h>

typedef short short8 __attribute__((ext_vector_type(8)));
typedef float f32x4 __attribute__((ext_vector_type(4)));

constexpr int Bc = 2, Hc = 16, NQc = 1024, NKc = 1024, DHc = 128;
constexpr int BQ = 16;        // q rows per block
constexpr int SP = 1028;      // ss row pitch (floats), pad for bank spread
constexpr int KP = 136;       // K/V/Q LDS row pitch (ushorts): 128 + 8
constexpr int PBP = 1040;     // p-bf16 LDS row pitch (ushorts)

__device__ __forceinline__ unsigned short f2bf(float f) {
  union { float f; unsigned u; } w; w.f = f;
  return (unsigned short)((w.u + 0x7FFFu + ((w.u >> 16) & 1u)) >> 16);  // RNE
}
__device__ __forceinline__ unsigned long long pack4(float a, float b, float c, float d) {
  return (unsigned long long)f2bf(a) | ((unsigned long long)f2bf(b) << 16)
       | ((unsigned long long)f2bf(c) << 32) | ((unsigned long long)f2bf(d) << 48);
}

__global__ __launch_bounds__(512, 2) void attn_fused(
    const float* __restrict__ qm, const float* __restrict__ km, const float* __restrict__ vm,
    const float* __restrict__ dq, const float* __restrict__ dkt, const float* __restrict__ dkb,
    const float* __restrict__ dks, const float* __restrict__ ww, const float* __restrict__ bw,
    const float* __restrict__ wb, const float* __restrict__ bb,
    float* __restrict__ outp, float* __restrict__ pp)
{
  __shared__ __align__(16) float ss[BQ * SP];                 // scores fp32; PV: aliased as vt (bf16 V^T)
  __shared__ __align__(16) unsigned short kpb[128 * KP];      // K-stage bf16; later: p bf16 [BQ][PBP]
  __shared__ __align__(16) unsigned short qsb[BQ * KP];       // Q-stage bf16
  __shared__ float e0s[128], cws[128], cbs[128], aws[BQ], abs_[BQ];

  const int wg = blockIdx.x;
  const int bid = (wg & 7) * 256 + (wg >> 3);   // bijective XCD swizzle (2048 % 8 == 0)
  const int qt = bid & 63, h = (bid >> 6) & 15, b = bid >> 10;
  const int q0 = qt * BQ;
  const int t = threadIdx.x;
  const int wv = t >> 6, lane = t & 63;
  const int bh = b * Hc + h;

  const float* qg = qm + ((size_t)bh * NQc + q0) * DHc;
  const float* kg = km + (size_t)bh * NKc * DHc;
  const float* vg = vm + (size_t)bh * NKc * DHc;

  // ---- Phase 0: stage Q tile (bf16), per-row Aw/Ab ----
  {
    int r = t >> 5;            // 0..15
    int c4 = (t & 31) * 4;     // 0..124
    float4 f = *(const float4*)(qg + r * DHc + c4);
    *(unsigned long long*)(&qsb[r * KP + c4]) = pack4(f.x, f.y, f.z, f.w);
  }
  if (t < BQ) {
    const float* dqr = dq + ((size_t)b * NQc + q0 + t) * 8;
    float4 a = *(const float4*)(dqr);
    float4 b4 = *(const float4*)(dqr + 4);
    float saw = 0.f, sab = 0.f;
    float dv[8] = {a.x, a.y, a.z, a.w, b4.x, b4.y, b4.z, b4.w};
#pragma unroll
    for (int d = 0; d < 8; ++d) {
      saw += dv[d] * ww[d * Hc + h];
      sab += dv[d] * wb[d * Hc + h];
    }
    aws[t] = saw; abs_[t] = sab;
  }
  __syncthreads();

  // Q fragments (persistent): A[m=lane&15][k = kk*32 + (lane>>4)*8 + j]
  short8 qf[4];
  {
    int rowb = (lane & 15) * KP;
    int ko = (lane >> 4) * 8;
#pragma unroll
    for (int kk = 0; kk < 4; ++kk)
      qf[kk] = *(const short8*)(&qsb[rowb + kk * 32 + ko]);
  }

  const float scale = 0.08838834764831845f;  // 1/sqrt(128)

  // ---- Phase 1: QK^T over 8 chunks of 128 k-rows, gated scores -> ss ----
  for (int kc = 0; kc < 8; ++kc) {
    const int k0 = kc * 128;
    __syncthreads();
    // stage K chunk: 128x128 fp32 -> bf16 LDS row-major [128][KP]
#pragma unroll
    for (int i = 0; i < 8; ++i) {
      int flat = i * 2048 + t * 4;
      int kr = flat >> 7, c = flat & 127;
      float4 f = *(const float4*)(kg + (size_t)(k0 + kr) * DHc + c);
      *(unsigned long long*)(&kpb[kr * KP + c]) = pack4(f.x, f.y, f.z, f.w);
    }
    // per-k scalars for this chunk
    if (t < 128) {
      int kk = k0 + t;
      const float* sc = dks + ((size_t)b * NKc + kk) * 2;
      float s0 = sc[0], s1 = sc[1];
      const float* tp = dkt + ((size_t)b * NKc + kk) * 8;
      const float* bt = dkb + ((size_t)b * NKc + kk) * 8;
      float4 t0 = *(const float4*)(tp), t1 = *(const float4*)(tp + 4);
      float4 b0 = *(const float4*)(bt), b1 = *(const float4*)(bt + 4);
      float tv[8] = {t0.x, t0.y, t0.z, t0.w, t1.x, t1.y, t1.z, t1.w};
      float bv[8] = {b0.x, b0.y, b0.z, b0.w, b1.x, b1.y, b1.z, b1.w};
      float cw = 0.f, cb = 0.f;
#pragma unroll
      for (int d = 0; d < 8; ++d) {
        float dk = tv[d] * s0 + bv[d] * s1;
        cw += dk * ww[d * Hc + h];
        cb += dk * wb[d * Hc + h];
      }
      e0s[t] = s0 + s1;
      cws[t] = cw - bw[h];
      cbs[t] = cb - bb[h];
    }
    __syncthreads();

    // MFMA: wave wv owns chunk-local cols [wv*16, wv*16+16)
    f32x4 acc = {0.f, 0.f, 0.f, 0.f};
    {
      int crow = (wv * 16 + (lane & 15)) * KP;
      int ko = (lane >> 4) * 8;
#pragma unroll
      for (int kk = 0; kk < 4; ++kk) {
        short8 bf = *(const short8*)(&kpb[crow + kk * 32 + ko]);
        acc = __builtin_amdgcn_mfma_f32_16x16x32_bf16(qf[kk], bf, acc, 0, 0, 0);
      }
    }
    // epilogue: gate + bias, store fp32 scores
    {
      int cl = wv * 16 + (lane & 15);
      int cglob = k0 + cl;
      float e0 = e0s[cl], cw2 = cws[cl], cb2 = cbs[cl];
      int rbase = (lane >> 4) * 4;
#pragma unroll
      for (int i = 0; i < 4; ++i) {
        int r = rbase + i;
        float s = acc[i] * scale;
        float x = e0 * aws[r] - cw2;
        float sp = (x > 20.f) ? x : log1pf(__expf(x));
        s = s * sp + (e0 * abs_[r] - cb2);
        ss[r * SP + cglob] = s;
      }
    }
  }
  __syncthreads();

  // ---- Phase 2: softmax (exact, fp32) + write p (global fp32, LDS bf16) ----
  unsigned short* pb = kpb;  // reuse K-stage region: 16*1040 = 16640 <= 17408
  {
    int r = t >> 5, g = t & 31;
    float m = -1e30f;
#pragma unroll
    for (int j = 0; j < 32; ++j) m = fmaxf(m, ss[r * SP + g + 32 * j]);
#pragma unroll
    for (int mk = 16; mk >= 1; mk >>= 1) m = fmaxf(m, __shfl_xor(m, mk, 64));
    float l = 0.f;
#pragma unroll
    for (int j = 0; j < 32; ++j) l += __expf(ss[r * SP + g + 32 * j] - m);
#pragma unroll
    for (int mk = 16; mk >= 1; mk >>= 1) l += __shfl_xor(l, mk, 64);
    float invl = 1.f / l;

    float* pgl = pp + ((size_t)bh * NQc + q0 + r) * (size_t)NKc;
#pragma unroll
    for (int j = 0; j < 8; ++j) {
      int c = g * 4 + j * 128;
      float4 sv = *(const float4*)(&ss[r * SP + c]);
      float4 pv;
      pv.x = __expf(sv.x - m) * invl;
      pv.y = __expf(sv.y - m) * invl;
      pv.z = __expf(sv.z - m) * invl;
      pv.w = __expf(sv.w - m) * invl;
      *(float4*)(pgl + c) = pv;
      *(unsigned long long*)(&pb[r * PBP + c]) = pack4(pv.x, pv.y, pv.z, pv.w);
    }
  }

  // ---- Phase 3: out = p @ V, V^T staged in LDS (aliases ss) ----
  unsigned short* vt = (unsigned short*)ss;  // [128 d][KP k-local]
  f32x4 oacc = {0.f, 0.f, 0.f, 0.f};
  for (int vc = 0; vc < 8; ++vc) {
    __syncthreads();
    // stage V chunk transposed: column-wise coalesced reads, b128 row writes
    {
      int c = t & 127, rq = t >> 7;
#pragma unroll
      for (int s8 = 0; s8 < 4; ++s8) {
        int kr0 = rq * 32 + s8 * 8;
        float vv[8];
#pragma unroll
        for (int j = 0; j < 8; ++j)
          vv[j] = vg[(size_t)(vc * 128 + kr0 + j) * DHc + c];
        unsigned long long lo = pack4(vv[0], vv[1], vv[2], vv[3]);
        unsigned long long hi = pack4(vv[4], vv[5], vv[6], vv[7]);
        *(unsigned long long*)(&vt[c * KP + kr0]) = lo;
        *(unsigned long long*)(&vt[c * KP + kr0 + 4]) = hi;
      }
    }
    __syncthreads();
    // MFMA: A = p rows (m=lane&15), B = V (n = d = wv*16 + (lane&15))
    {
      int prow = (lane & 15) * PBP;
      int vrow = (wv * 16 + (lane & 15)) * KP;
      int ko = (lane >> 4) * 8;
#pragma unroll
      for (int kt = 0; kt < 4; ++kt) {
        short8 af = *(const short8*)(&pb[prow + vc * 128 + kt * 32 + ko]);
        short8 bf = *(const short8*)(&vt[vrow + kt * 32 + ko]);
        oacc = __builtin_amdgcn_mfma_f32_16x16x32_bf16(af, bf, oacc, 0, 0, 0);
      }
    }
  }

  // ---- write out[b,h,q0+r,d] ----
  {
    int d = wv * 16 + (lane & 15);
    int rb = (lane >> 4) * 4;
#pragma unroll
    for (int i = 0; i < 4; ++i)
      outp[((size_t)bh * NQc + q0 + rb + i) * DHc + d] = oacc[i];
  }
}

extern "C" void kernel_launch(void* const* d_in, const int* in_sizes, int n_in,
                              void* d_out, int out_size, void* d_ws, size_t ws_size,
                              hipStream_t stream) {
  (void)in_sizes; (void)n_in; (void)d_ws; (void)ws_size; (void)out_size;
  const float* q   = (const float*)d_in[0];
  const float* k   = (const float*)d_in[1];
  const float* v   = (const float*)d_in[2];
  // d_in[3] = c (unused, is_leaky=False)
  const float* dq  = (const float*)d_in[4];
  const float* dkt = (const float*)d_in[5];
  const float* dkb = (const float*)d_in[6];
  const float* dks = (const float*)d_in[7];
  const float* ww  = (const float*)d_in[8];
  const float* bw  = (const float*)d_in[9];
  const float* wb  = (const float*)d_in[10];
  const float* bb  = (const float*)d_in[11];
  float* outp = (float*)d_out;
  float* pp   = outp + (size_t)Bc * Hc * NQc * DHc;

  hipLaunchKernelGGL(attn_fused, dim3(2048), dim3(512), 0, stream,
                     q, k, v, dq, dkt, dkb, dks, ww, bw, wb, bb, outp, pp);
}

// Round 2
// 343.484 us; speedup vs baseline: 1.4693x; 1.4693x over previous
//
#include <hip/hip_runtime.h>

typedef short short8 __attribute__((ext_vector_type(8)));
typedef float f32x4 __attribute__((ext_vector_type(4)));

constexpr int Bc = 2, Hc = 16, NQc = 1024, NKc = 1024, DHc = 128;
constexpr int BQ = 16;
constexpr int PBP = 1032;                    // p-bf16 LDS pitch (shorts): 2064B row ≡ 4 dwords mod 32 banks
constexpr size_t KBF_ELEMS = (size_t)Bc * Hc * NKc * DHc;   // 4,194,304 shorts

__device__ __forceinline__ unsigned short f2bf(float f) {
  union { float f; unsigned u; } w; w.f = f;
  return (unsigned short)((w.u + 0x7FFFu + ((w.u >> 16) & 1u)) >> 16);  // RNE
}
__device__ __forceinline__ float bf2f(unsigned short s) {
  union { unsigned u; float f; } w; w.u = ((unsigned)s) << 16; return w.f;
}
__device__ __forceinline__ unsigned long long pack4(float a, float b, float c, float d) {
  return (unsigned long long)f2bf(a) | ((unsigned long long)f2bf(b) << 16)
       | ((unsigned long long)f2bf(c) << 32) | ((unsigned long long)f2bf(d) << 48);
}

typedef __attribute__((address_space(1))) const unsigned int glb_u32;
typedef __attribute__((address_space(3))) unsigned int lds_u32;
// LDS dest = wave-uniform base + lane*16 (HW); global src is per-lane.
__device__ __forceinline__ void gl16(const void* g, void* l) {
  __builtin_amdgcn_global_load_lds((glb_u32*)g, (lds_u32*)l, 16, 0, 0);
}

// ---------------- pre-pass: K -> bf16, V -> V^T bf16 ----------------
__global__ __launch_bounds__(256) void prep(const float* __restrict__ km,
                                            const float* __restrict__ vm,
                                            unsigned short* __restrict__ kbf,
                                            unsigned short* __restrict__ vtb) {
  const int blk = blockIdx.x, t = threadIdx.x;
  if (blk < 1024) {
    // V^T: 64x64 tile transpose per block. 32 bh * (16 k-tiles x 2 d-tiles)
    __shared__ float tile[64][65];
    const int bh = blk >> 5, tl = blk & 31;
    const int k0 = (tl & 15) * 64, d0 = (tl >> 4) * 64;
    const float* vsrc = vm + ((size_t)bh * NKc + k0) * DHc + d0;
    {
      int j = t & 63, i0 = t >> 6;
#pragma unroll
      for (int s = 0; s < 16; ++s) {
        int i = i0 + s * 4;
        tile[i][j] = vsrc[(size_t)i * DHc + j];
      }
    }
    __syncthreads();
    unsigned short* vdst = vtb + ((size_t)bh * DHc + d0) * NKc + k0;
    {
      int i2 = (t & 15) * 4, j0 = t >> 4;
#pragma unroll
      for (int s = 0; s < 4; ++s) {
        int j2 = j0 + s * 16;
        float a0 = tile[i2 + 0][j2], a1 = tile[i2 + 1][j2];
        float a2 = tile[i2 + 2][j2], a3 = tile[i2 + 3][j2];
        *(unsigned long long*)(vdst + (size_t)j2 * NKc + i2) = pack4(a0, a1, a2, a3);
      }
    }
  } else {
    // K convert: 2048 blocks * 256 threads * 2 float4 = 1,048,576 float4
    const float4* kf4 = (const float4*)km;
#pragma unroll
    for (int rep = 0; rep < 2; ++rep) {
      size_t g = (size_t)(blk - 1024) * 256 + t + (size_t)rep * 524288;
      float4 f = kf4[g];
      *(unsigned long long*)(kbf + g * 4) = pack4(f.x, f.y, f.z, f.w);
    }
  }
}

// ---------------- main fused attention ----------------
__global__ __launch_bounds__(512, 4) void attn_main(
    const float* __restrict__ qm, const unsigned short* __restrict__ kbf,
    const unsigned short* __restrict__ vtb,
    const float* __restrict__ dq, const float* __restrict__ dkt, const float* __restrict__ dkb,
    const float* __restrict__ dks, const float* __restrict__ ww, const float* __restrict__ bw,
    const float* __restrict__ wb, const float* __restrict__ bb,
    float* __restrict__ outp, float* __restrict__ pp)
{
  // kv: 128x128 bf16 chunk (K, then V^T), XOR-swizzled slots, linear for global_load_lds. 32 KB
  __shared__ __align__(16) unsigned short kv[16384];
  __shared__ __align__(16) unsigned short pbs[BQ * PBP];   // 33 KB p bf16
  __shared__ float e0s[1024], cws[1024], cbs[1024];        // 12 KB gate scalars
  __shared__ float aws[BQ], abs_[BQ];
  __shared__ float redm[128], redl[128];

  const int wg = blockIdx.x;
  const int bid = (wg & 7) * 256 + (wg >> 3);   // bijective XCD swizzle (2048 % 8 == 0)
  const int qt = bid & 63, h = (bid >> 6) & 15, b = bid >> 10;
  const int q0 = qt * BQ;
  const int t = threadIdx.x, wv = t >> 6, lane = t & 63;
  const int hi = lane >> 4, lo = lane & 15;
  const int bh = b * Hc + h;

  // ---- gate scalar precompute: per-k (1024) and per-q-row (16) ----
  {
    float whc[8], wbc[8];
#pragma unroll
    for (int d = 0; d < 8; ++d) { whc[d] = ww[d * Hc + h]; wbc[d] = wb[d * Hc + h]; }
    float bwh = bw[h], bbh = bb[h];
#pragma unroll
    for (int rep = 0; rep < 2; ++rep) {
      int kk = t + rep * 512;
      const float* sc = dks + ((size_t)b * NKc + kk) * 2;
      float s0 = sc[0], s1 = sc[1];
      const float* tp = dkt + ((size_t)b * NKc + kk) * 8;
      const float* bp = dkb + ((size_t)b * NKc + kk) * 8;
      float4 t0 = *(const float4*)tp, t1 = *(const float4*)(tp + 4);
      float4 b0 = *(const float4*)bp, b1 = *(const float4*)(bp + 4);
      float tv[8] = {t0.x, t0.y, t0.z, t0.w, t1.x, t1.y, t1.z, t1.w};
      float bv[8] = {b0.x, b0.y, b0.z, b0.w, b1.x, b1.y, b1.z, b1.w};
      float cw = 0.f, cb = 0.f;
#pragma unroll
      for (int d = 0; d < 8; ++d) {
        float dk = tv[d] * s0 + bv[d] * s1;
        cw += dk * whc[d];
        cb += dk * wbc[d];
      }
      e0s[kk] = s0 + s1;
      cws[kk] = cw - bwh;
      cbs[kk] = cb - bbh;
    }
    if (t < BQ) {
      const float* dqr = dq + ((size_t)b * NQc + q0 + t) * 8;
      float4 a = *(const float4*)dqr, b4 = *(const float4*)(dqr + 4);
      float dv[8] = {a.x, a.y, a.z, a.w, b4.x, b4.y, b4.z, b4.w};
      float saw = 0.f, sab = 0.f;
#pragma unroll
      for (int d = 0; d < 8; ++d) { saw += dv[d] * whc[d]; sab += dv[d] * wbc[d]; }
      aws[t] = saw; abs_[t] = sab;
    }
  }

  // ---- Q fragments direct from global fp32 (A[m=lo][k = kk*32 + hi*8 + j]) ----
  short8 qf[4];
  {
    const float* qg = qm + ((size_t)bh * NQc + q0 + lo) * DHc + hi * 8;
#pragma unroll
    for (int kk = 0; kk < 4; ++kk) {
      float4 a = *(const float4*)(qg + kk * 32);
      float4 c = *(const float4*)(qg + kk * 32 + 4);
      union { short8 v; unsigned long long u[2]; } q8;
      q8.u[0] = pack4(a.x, a.y, a.z, a.w);
      q8.u[1] = pack4(c.x, c.y, c.z, c.w);
      qf[kk] = q8.v;
    }
  }

  const float scale = 0.08838834764831845f;  // 1/sqrt(128)
  const unsigned short* kg = kbf + (size_t)bh * NKc * DHc;
  const unsigned short* vtg = vtb + (size_t)bh * DHc * NKc;

  // ---- Phase 1: QK^T, 8 chunks of 128 keys; scores stay in registers ----
  f32x4 sacc[8];
#pragma unroll 1
  for (int kc = 0; kc < 8; ++kc) {
    __syncthreads();   // kv free (prev chunk MFMA done); also fences gate precompute (kc==0)
    // stage K chunk: linear LDS dest, XOR-swizzled global source (slot ^= row&15)
#pragma unroll
    for (int r = 0; r < 4; ++r) {
      int base = ((r << 3) + wv) << 10;        // wave-uniform byte base
      int F = base + (lane << 4);              // this lane's dest byte
      int kr = F >> 8;
      int gslot = ((F >> 4) & 15) ^ (kr & 15);
      const unsigned short* gp = kg + ((size_t)(kc * 128 + kr) << 7) + (gslot << 3);
      gl16(gp, (char*)kv + base);
    }
    __syncthreads();
    f32x4 acc = {0.f, 0.f, 0.f, 0.f};
    {
      int kr = (wv << 4) + lo;                 // chunk-local key = B-frag n
#pragma unroll
      for (int kk = 0; kk < 4; ++kk) {
        short8 bf = *(const short8*)&kv[(kr << 7) + (((((kk << 2) + hi)) ^ (kr & 15)) << 3)];
        acc = __builtin_amdgcn_mfma_f32_16x16x32_bf16(qf[kk], bf, acc, 0, 0, 0);
      }
      int cg = kc * 128 + kr;
      float e0 = e0s[cg], cw2 = cws[cg], cb2 = cbs[cg];
      int rb = hi << 2;
#pragma unroll
      for (int i = 0; i < 4; ++i) {
        float s = acc[i] * scale;
        float x = e0 * aws[rb + i] - cw2;
        float sp = (x > 20.f) ? x : log1pf(__expf(x));
        acc[i] = s * sp + (e0 * abs_[rb + i] - cb2);
      }
    }
    sacc[kc] = acc;
  }

  // ---- Phase 2: exact softmax over registers ----
  const int rb = hi << 2;
  float m4[4], inv4[4];
#pragma unroll
  for (int i = 0; i < 4; ++i) {
    float pm = sacc[0][i];
#pragma unroll
    for (int kc = 1; kc < 8; ++kc) pm = fmaxf(pm, sacc[kc][i]);
    pm = fmaxf(pm, __shfl_xor(pm, 1, 64));
    pm = fmaxf(pm, __shfl_xor(pm, 2, 64));
    pm = fmaxf(pm, __shfl_xor(pm, 4, 64));
    pm = fmaxf(pm, __shfl_xor(pm, 8, 64));
    m4[i] = pm;
  }
  if (lo == 0) {
#pragma unroll
    for (int i = 0; i < 4; ++i) redm[(wv << 4) + rb + i] = m4[i];
  }
  __syncthreads();
#pragma unroll
  for (int i = 0; i < 4; ++i) {
    float m = redm[rb + i];
#pragma unroll
    for (int w = 1; w < 8; ++w) m = fmaxf(m, redm[(w << 4) + rb + i]);
    m4[i] = m;
  }
#pragma unroll
  for (int i = 0; i < 4; ++i) {
    float pl = 0.f;
#pragma unroll
    for (int kc = 0; kc < 8; ++kc) {
      float e = __expf(sacc[kc][i] - m4[i]);
      sacc[kc][i] = e;
      pl += e;
    }
    pl += __shfl_xor(pl, 1, 64);
    pl += __shfl_xor(pl, 2, 64);
    pl += __shfl_xor(pl, 4, 64);
    pl += __shfl_xor(pl, 8, 64);
    inv4[i] = pl;
  }
  if (lo == 0) {
#pragma unroll
    for (int i = 0; i < 4; ++i) redl[(wv << 4) + rb + i] = inv4[i];
  }
  __syncthreads();
#pragma unroll
  for (int i = 0; i < 4; ++i) {
    float l = redl[rb + i];
#pragma unroll
    for (int w = 1; w < 8; ++w) l += redl[(w << 4) + rb + i];
    inv4[i] = 1.f / l;
  }
  // p -> bf16 LDS (feeds both PV A-operand and the global p write)
#pragma unroll
  for (int i = 0; i < 4; ++i) {
    int prow = (rb + i) * PBP + (wv << 4) + lo;
#pragma unroll
    for (int kc = 0; kc < 8; ++kc)
      pbs[prow + (kc << 7)] = f2bf(sacc[kc][i] * inv4[i]);
  }

  // ---- Phase 3: out = p @ V via V^T chunks; p global write interleaved ----
  f32x4 oacc = {0.f, 0.f, 0.f, 0.f};
#pragma unroll 1
  for (int vc = 0; vc < 8; ++vc) {
    __syncthreads();   // kv free; (vc==0) also fences pbs writes
#pragma unroll
    for (int r = 0; r < 4; ++r) {
      int base = ((r << 3) + wv) << 10;
      int F = base + (lane << 4);
      int dd = F >> 8;
      int gslot = ((F >> 4) & 15) ^ (dd & 15);
      const unsigned short* gp = vtg + ((size_t)dd << 10) + (vc << 7) + (gslot << 3);
      gl16(gp, (char*)kv + base);
    }
    // p global write for this chunk's 128 columns (hides under V staging)
    {
      int row = t >> 5, c4 = (t & 31) * 4;
      unsigned long long u = *(const unsigned long long*)&pbs[row * PBP + (vc << 7) + c4];
      float4 o;
      o.x = bf2f((unsigned short)u);
      o.y = bf2f((unsigned short)(u >> 16));
      o.z = bf2f((unsigned short)(u >> 32));
      o.w = bf2f((unsigned short)(u >> 48));
      *(float4*)&pp[((size_t)bh * NQc + q0 + row) * (size_t)NKc + (vc << 7) + c4] = o;
    }
    __syncthreads();
    {
      int dn = (wv << 4) + lo;                 // output dim = B-frag n
#pragma unroll
      for (int kt = 0; kt < 4; ++kt) {
        short8 af = *(const short8*)&pbs[lo * PBP + (vc << 7) + (kt << 5) + (hi << 3)];
        short8 bf = *(const short8*)&kv[(dn << 7) + (((((kt << 2) + hi)) ^ (dn & 15)) << 3)];
        oacc = __builtin_amdgcn_mfma_f32_16x16x32_bf16(af, bf, oacc, 0, 0, 0);
      }
    }
  }

  // ---- out[b,h,q,d] ----
  {
    int dn = (wv << 4) + lo;
#pragma unroll
    for (int i = 0; i < 4; ++i)
      outp[((size_t)bh * NQc + q0 + rb + i) * DHc + dn] = oacc[i];
  }
}

extern "C" void kernel_launch(void* const* d_in, const int* in_sizes, int n_in,
                              void* d_out, int out_size, void* d_ws, size_t ws_size,
                              hipStream_t stream) {
  (void)in_sizes; (void)n_in; (void)out_size; (void)ws_size;
  const float* q   = (const float*)d_in[0];
  const float* k   = (const float*)d_in[1];
  const float* v   = (const float*)d_in[2];
  const float* dq  = (const float*)d_in[4];
  const float* dkt = (const float*)d_in[5];
  const float* dkb = (const float*)d_in[6];
  const float* dks = (const float*)d_in[7];
  const float* ww  = (const float*)d_in[8];
  const float* bw  = (const float*)d_in[9];
  const float* wb  = (const float*)d_in[10];
  const float* bb  = (const float*)d_in[11];
  float* outp = (float*)d_out;
  float* pp   = outp + (size_t)Bc * Hc * NQc * DHc;

  unsigned short* kbf = (unsigned short*)d_ws;          // 8.39 MB
  unsigned short* vtb = kbf + KBF_ELEMS;                // 8.39 MB  (ws needs 16.8 MB)

  hipLaunchKernelGGL(prep, dim3(3072), dim3(256), 0, stream, k, v, kbf, vtb);
  hipLaunchKernelGGL(attn_main, dim3(2048), dim3(512), 0, stream,
                     q, kbf, vtb, dq, dkt, dkb, dks, ww, bw, wb, bb, outp, pp);
}

// Round 6
// 278.310 us; speedup vs baseline: 1.8133x; 1.2342x over previous
//
#include <hip/hip_runtime.h>

typedef short short8 __attribute__((ext_vector_type(8)));
typedef float f32x4 __attribute__((ext_vector_type(4)));

constexpr int Bc = 2, Hc = 16, NQc = 1024, NKc = 1024, DHc = 128;
constexpr int BQ = 16;
constexpr int PBP = 1032;                    // p-bf16 LDS pitch (shorts); rows 16B-aligned
constexpr size_t KBF_ELEMS = (size_t)Bc * Hc * NKc * DHc;   // 4,194,304 shorts

__device__ __forceinline__ unsigned cvtpk(float a, float b) {  // HW RNE f32x2 -> bf16x2
  unsigned r;
  asm("v_cvt_pk_bf16_f32 %0, %1, %2" : "=v"(r) : "v"(a), "v"(b));
  return r;
}
__device__ __forceinline__ unsigned long long pack4(float a, float b, float c, float d) {
  return (unsigned long long)cvtpk(a, b) | ((unsigned long long)cvtpk(c, d) << 32);
}
__device__ __forceinline__ float bfbits(unsigned u) {  // u must be (bf16 << 16)
  union { unsigned x; float f; } w; w.x = u; return w.f;
}

typedef __attribute__((address_space(1))) const unsigned int glb_u32;
typedef __attribute__((address_space(3))) unsigned int lds_u32;
__device__ __forceinline__ void gl16(const void* g, void* l) {
  __builtin_amdgcn_global_load_lds((glb_u32*)g, (lds_u32*)l, 16, 0, 0);
}

// ---------------- pre-pass: K -> bf16, V -> V^T bf16 ----------------
__global__ __launch_bounds__(256) void prep(const float* __restrict__ km,
                                            const float* __restrict__ vm,
                                            unsigned short* __restrict__ kbf,
                                            unsigned short* __restrict__ vtb) {
  const int blk = blockIdx.x, t = threadIdx.x;
  if (blk < 1024) {
    // V^T: 64x64 tile transpose per block. 32 bh * (16 k-tiles x 2 d-tiles)
    __shared__ float tile[64][65];
    const int bh = blk >> 5, tl = blk & 31;
    const int k0 = (tl & 15) * 64, d0 = (tl >> 4) * 64;
    const float* vsrc = vm + ((size_t)bh * NKc + k0) * DHc + d0;
    {
      int j = t & 63, i0 = t >> 6;
#pragma unroll
      for (int s = 0; s < 16; ++s) {
        int i = i0 + s * 4;
        tile[i][j] = vsrc[(size_t)i * DHc + j];
      }
    }
    __syncthreads();
    unsigned short* vdst = vtb + ((size_t)bh * DHc + d0) * NKc + k0;
    {
      int i2 = (t & 15) * 4, j0 = t >> 4;
#pragma unroll
      for (int s = 0; s < 4; ++s) {
        int j2 = j0 + s * 16;
        float a0 = tile[i2 + 0][j2], a1 = tile[i2 + 1][j2];
        float a2 = tile[i2 + 2][j2], a3 = tile[i2 + 3][j2];
        *(unsigned long long*)(vdst + (size_t)j2 * NKc + i2) = pack4(a0, a1, a2, a3);
      }
    }
  } else {
    const float4* kf4 = (const float4*)km;
#pragma unroll
    for (int rep = 0; rep < 2; ++rep) {
      size_t g = (size_t)(blk - 1024) * 256 + t + (size_t)rep * 524288;
      float4 f = kf4[g];
      *(unsigned long long*)(kbf + g * 4) = pack4(f.x, f.y, f.z, f.w);
    }
  }
}

// ---------------- main fused attention ----------------
__global__ __launch_bounds__(512, 4) void attn_main(
    const float* __restrict__ qm, const unsigned short* __restrict__ kbf,
    const unsigned short* __restrict__ vtb,
    const float* __restrict__ dq, const float* __restrict__ dkt, const float* __restrict__ dkb,
    const float* __restrict__ dks, const float* __restrict__ ww, const float* __restrict__ bw,
    const float* __restrict__ wb, const float* __restrict__ bb,
    float* __restrict__ outp, float* __restrict__ pp)
{
  __shared__ __align__(16) unsigned short kv[16384];       // 32 KB K / V^T chunk (swizzled slots)
  __shared__ __align__(16) unsigned short pbs[BQ * PBP];   // 33 KB p bf16
  __shared__ float e0s[1024], cws[1024], cbs[1024];        // 12 KB gate scalars
  __shared__ float aws[BQ], abs_[BQ];
  __shared__ float redm[128], redl[128];

  const int wg = blockIdx.x;
  const int bid = (wg & 7) * 256 + (wg >> 3);   // bijective XCD swizzle (2048 % 8 == 0)
  const int qt = bid & 63, h = (bid >> 6) & 15, b = bid >> 10;
  const int q0 = qt * BQ;
  const int t = threadIdx.x, wv = t >> 6, lane = t & 63;
  const int hi = lane >> 4, lo = lane & 15;
  const int rb = hi << 2;
  const int bh = b * Hc + h;

  // ---- gate scalar precompute ----
  {
    float whc[8], wbc[8];
#pragma unroll
    for (int d = 0; d < 8; ++d) { whc[d] = ww[d * Hc + h]; wbc[d] = wb[d * Hc + h]; }
    float bwh = bw[h], bbh = bb[h];
#pragma unroll
    for (int rep = 0; rep < 2; ++rep) {
      int kk = t + rep * 512;
      const float* sc = dks + ((size_t)b * NKc + kk) * 2;
      float s0 = sc[0], s1 = sc[1];
      const float* tp = dkt + ((size_t)b * NKc + kk) * 8;
      const float* bp = dkb + ((size_t)b * NKc + kk) * 8;
      float4 t0 = *(const float4*)tp, t1 = *(const float4*)(tp + 4);
      float4 b0 = *(const float4*)bp, b1 = *(const float4*)(bp + 4);
      float tv[8] = {t0.x, t0.y, t0.z, t0.w, t1.x, t1.y, t1.z, t1.w};
      float bv[8] = {b0.x, b0.y, b0.z, b0.w, b1.x, b1.y, b1.z, b1.w};
      float cw = 0.f, cb = 0.f;
#pragma unroll
      for (int d = 0; d < 8; ++d) {
        float dk = tv[d] * s0 + bv[d] * s1;
        cw += dk * whc[d];
        cb += dk * wbc[d];
      }
      e0s[kk] = s0 + s1;
      cws[kk] = cw - bwh;
      cbs[kk] = cb - bbh;
    }
    if (t < BQ) {
      const float* dqr = dq + ((size_t)b * NQc + q0 + t) * 8;
      float4 a = *(const float4*)dqr, b4 = *(const float4*)(dqr + 4);
      float dv[8] = {a.x, a.y, a.z, a.w, b4.x, b4.y, b4.z, b4.w};
      float saw = 0.f, sab = 0.f;
#pragma unroll
      for (int d = 0; d < 8; ++d) { saw += dv[d] * whc[d]; sab += dv[d] * wbc[d]; }
      aws[t] = saw; abs_[t] = sab;
    }
  }

  // ---- Q fragments direct from global fp32 (A[m=lo][k = kk*32 + hi*8 + j]) ----
  short8 qf[4];
  {
    const float* qg = qm + ((size_t)bh * NQc + q0 + lo) * DHc + hi * 8;
#pragma unroll
    for (int kk = 0; kk < 4; ++kk) {
      float4 a = *(const float4*)(qg + kk * 32);
      float4 c = *(const float4*)(qg + kk * 32 + 4);
      union { short8 v; unsigned long long u[2]; } q8;
      q8.u[0] = pack4(a.x, a.y, a.z, a.w);
      q8.u[1] = pack4(c.x, c.y, c.z, c.w);
      qf[kk] = q8.v;
    }
  }

  const float scale = 0.08838834764831845f;  // 1/sqrt(128)
  const unsigned short* kg = kbf + (size_t)bh * NKc * DHc;
  const unsigned short* vtg = vtb + (size_t)bh * DHc * NKc;

  // ---- hoisted per-lane staging descriptors & MFMA LDS offsets ----
  const unsigned short* ksrc[4];   // K chunk src (without kc term)
  const unsigned short* vsrc[4];   // V^T chunk src (without vc term)
  char* ldst[4];                   // generic pointers; addrspace cast inside gl16
#pragma unroll
  for (int r = 0; r < 4; ++r) {
    int base = ((r << 3) + wv) << 10;          // wave-uniform dest byte base
    int F = base + (lane << 4);
    int kr = F >> 8;                            // dest row (key or d-dim)
    int gslot = ((F >> 4) & 15) ^ (kr & 15);    // inverse-swizzled source slot
    ksrc[r] = kg + ((size_t)kr << 7) + (gslot << 3);
    vsrc[r] = vtg + ((size_t)kr << 10) + (gslot << 3);
    ldst[r] = (char*)kv + base;
  }
  const int kr16 = (wv << 4) + lo;              // B-frag n (key idx / d idx)
  int qoff[4];                                  // swizzled B-frag LDS offsets (shorts)
#pragma unroll
  for (int kk = 0; kk < 4; ++kk)
    qoff[kk] = (kr16 << 7) + (((((kk << 2) + hi)) ^ (kr16 & 15)) << 3);

  __syncthreads();   // fence gate-scalar writes
  float aw4[4], ab4[4];
#pragma unroll
  for (int i = 0; i < 4; ++i) { aw4[i] = aws[rb + i]; ab4[i] = abs_[rb + i]; }

  // ---- Phase 1: QK^T + gate, scores stay in registers ----
  f32x4 sacc[8];
#pragma unroll 1
  for (int kc = 0; kc < 8; ++kc) {
    __syncthreads();
#pragma unroll
    for (int r = 0; r < 4; ++r)
      gl16(ksrc[r] + ((size_t)kc << 14), ldst[r]);
    __syncthreads();
    f32x4 acc = {0.f, 0.f, 0.f, 0.f};
#pragma unroll
    for (int kk = 0; kk < 4; ++kk)
      acc = __builtin_amdgcn_mfma_f32_16x16x32_bf16(qf[kk], *(const short8*)&kv[qoff[kk]], acc, 0, 0, 0);
    int cg = (kc << 7) + kr16;
    float e0 = e0s[cg], cw2 = cws[cg], cb2 = cbs[cg];
#pragma unroll
    for (int i = 0; i < 4; ++i) {
      float s = acc[i] * scale;
      float x = fmaf(e0, aw4[i], -cw2);
      float ex = __expf(x);
      float sp = (x > 20.f) ? x : __logf(1.f + ex);   // softplus, cheap form
      acc[i] = fmaf(s, sp, fmaf(e0, ab4[i], -cb2));
    }
    sacc[kc] = acc;
  }

  // ---- Phase 2: exact softmax over registers ----
  float m4[4], inv4[4];
#pragma unroll
  for (int i = 0; i < 4; ++i) {
    float pm = sacc[0][i];
#pragma unroll
    for (int kc = 1; kc < 8; ++kc) pm = fmaxf(pm, sacc[kc][i]);
    pm = fmaxf(pm, __shfl_xor(pm, 1, 64));
    pm = fmaxf(pm, __shfl_xor(pm, 2, 64));
    pm = fmaxf(pm, __shfl_xor(pm, 4, 64));
    pm = fmaxf(pm, __shfl_xor(pm, 8, 64));
    m4[i] = pm;
  }
  if (lo == 0) {
#pragma unroll
    for (int i = 0; i < 4; ++i) redm[(wv << 4) + rb + i] = m4[i];
  }
  __syncthreads();
#pragma unroll
  for (int i = 0; i < 4; ++i) {
    float m = redm[rb + i];
#pragma unroll
    for (int w = 1; w < 8; ++w) m = fmaxf(m, redm[(w << 4) + rb + i]);
    m4[i] = m;
  }
#pragma unroll
  for (int i = 0; i < 4; ++i) {
    float pl = 0.f;
#pragma unroll
    for (int kc = 0; kc < 8; ++kc) {
      float e = __expf(sacc[kc][i] - m4[i]);
      sacc[kc][i] = e;
      pl += e;
    }
    pl += __shfl_xor(pl, 1, 64);
    pl += __shfl_xor(pl, 2, 64);
    pl += __shfl_xor(pl, 4, 64);
    pl += __shfl_xor(pl, 8, 64);
    inv4[i] = pl;
  }
  if (lo == 0) {
#pragma unroll
    for (int i = 0; i < 4; ++i) redl[(wv << 4) + rb + i] = inv4[i];
  }
  __syncthreads();
#pragma unroll
  for (int i = 0; i < 4; ++i) {
    float l = redl[rb + i];
#pragma unroll
    for (int w = 1; w < 8; ++w) l += redl[(w << 4) + rb + i];
    inv4[i] = 1.f / l;
  }
  // p -> bf16 LDS via HW cvt_pk (16 cvt + 16 shifts instead of 32 soft-f2bf)
#pragma unroll
  for (int i = 0; i < 4; ++i) {
    int prow = (rb + i) * PBP + kr16;
    float iv = inv4[i];
#pragma unroll
    for (int k2 = 0; k2 < 4; ++k2) {
      unsigned u = cvtpk(sacc[2 * k2][i] * iv, sacc[2 * k2 + 1][i] * iv);
      pbs[prow + ((2 * k2) << 7)] = (unsigned short)u;
      pbs[prow + ((2 * k2 + 1) << 7)] = (unsigned short)(u >> 16);
    }
  }

  // ---- Phase 3: out = p @ V via V^T chunks; p global write interleaved ----
  const int pA = lo * PBP + (hi << 3);          // A-frag base (shorts)
  const int prow_w = t >> 5, pc4 = (t & 31) * 4;
  const unsigned short* pbr = &pbs[prow_w * PBP + pc4];
  float* pgl = pp + ((size_t)bh * NQc + q0 + prow_w) * (size_t)NKc + pc4;
  f32x4 oacc = {0.f, 0.f, 0.f, 0.f};
#pragma unroll 1
  for (int vc = 0; vc < 8; ++vc) {
    __syncthreads();   // kv free; (vc==0) also fences pbs writes
#pragma unroll
    for (int r = 0; r < 4; ++r)
      gl16(vsrc[r] + (vc << 7), ldst[r]);
    // p global write for this chunk's 128 columns (overlaps V staging)
    {
      unsigned long long u = *(const unsigned long long*)(pbr + (vc << 7));
      unsigned l32 = (unsigned)u, h32 = (unsigned)(u >> 32);
      float4 o;
      o.x = bfbits(l32 << 16);
      o.y = bfbits(l32 & 0xffff0000u);
      o.z = bfbits(h32 << 16);
      o.w = bfbits(h32 & 0xffff0000u);
      *(float4*)(pgl + (vc << 7)) = o;
    }
    __syncthreads();
#pragma unroll
    for (int kt = 0; kt < 4; ++kt) {
      short8 af = *(const short8*)&pbs[pA + (vc << 7) + (kt << 5)];
      short8 bf = *(const short8*)&kv[qoff[kt]];
      oacc = __builtin_amdgcn_mfma_f32_16x16x32_bf16(af, bf, oacc, 0, 0, 0);
    }
  }

  // ---- out[b,h,q,d] ----
#pragma unroll
  for (int i = 0; i < 4; ++i)
    outp[((size_t)bh * NQc + q0 + rb + i) * DHc + kr16] = oacc[i];
}

extern "C" void kernel_launch(void* const* d_in, const int* in_sizes, int n_in,
                              void* d_out, int out_size, void* d_ws, size_t ws_size,
                              hipStream_t stream) {
  (void)in_sizes; (void)n_in; (void)out_size; (void)ws_size;
  const float* q   = (const float*)d_in[0];
  const float* k   = (const float*)d_in[1];
  const float* v   = (const float*)d_in[2];
  const float* dq  = (const float*)d_in[4];
  const float* dkt = (const float*)d_in[5];
  const float* dkb = (const float*)d_in[6];
  const float* dks = (const float*)d_in[7];
  const float* ww  = (const float*)d_in[8];
  const float* bw  = (const float*)d_in[9];
  const float* wb  = (const float*)d_in[10];
  const float* bb  = (const float*)d_in[11];
  float* outp = (float*)d_out;
  float* pp   = outp + (size_t)Bc * Hc * NQc * DHc;

  unsigned short* kbf = (unsigned short*)d_ws;          // 8.39 MB
  unsigned short* vtb = kbf + KBF_ELEMS;                // 8.39 MB

  hipLaunchKernelGGL(prep, dim3(3072), dim3(256), 0, stream, k, v, kbf, vtb);
  hipLaunchKernelGGL(attn_main, dim3(2048), dim3(512), 0, stream,
                     q, kbf, vtb, dq, dkt, dkb, dks, ww, bw, wb, bb, outp, pp);
}